// Round 14
// baseline (241.845 us; speedup 1.0000x reference)
//
#include <hip/hip_runtime.h>
#include <stdint.h>
#include <stddef.h>

#define D_MODEL 1024
#define NHEAD   16
#define DK      64
#define BB      2
#define SS      2048
#define NTOK    (BB*SS)   // 4096

// log2(e) / sqrt(Dk) folded into the Q projection output:
#define SCALE_Q 0.18033688011f

typedef __bf16 bf16x8 __attribute__((ext_vector_type(8)));
typedef float  f32x4  __attribute__((ext_vector_type(4)));

// pack two f32 -> two bf16 (round-half-up) in 3 VALU: add, add, v_perm
__device__ __forceinline__ unsigned int pack_bf2(float x, float y){
  unsigned int a = __builtin_bit_cast(unsigned int, x) + 0x8000u;
  unsigned int b = __builtin_bit_cast(unsigned int, y) + 0x8000u;
  return __builtin_amdgcn_perm(b, a, 0x07060302u);  // [y_hi16 | x_hi16]
}

// two f32 -> packed bf16x2 in ONE VALU (RNE). dst.lo = lo, dst.hi = hi.
__device__ __forceinline__ unsigned int cvt_pk_bf16(float lo, float hi){
  unsigned int r;
  asm("v_cvt_pk_bf16_f32 %0, %1, %2" : "=v"(r) : "v"(lo), "v"(hi));
  return r;
}

__device__ __forceinline__ float fast_exp2(float x){
#if __has_builtin(__builtin_amdgcn_exp2f)
  return __builtin_amdgcn_exp2f(x);   // raw v_exp_f32; args bounded, no denorms
#else
  return exp2f(x);
#endif
}

__device__ __forceinline__ f32x4 mfma16(bf16x8 a, bf16x8 b, f32x4 c){
  return __builtin_amdgcn_mfma_f32_16x16x32_bf16(a, b, c, 0, 0, 0);
}

// async global->LDS, 16B/lane; LDS dst = wave-uniform base + lane*16
__device__ __forceinline__ void async16(const void* g, void* lds){
  __builtin_amdgcn_global_load_lds(
      (const __attribute__((address_space(1))) unsigned int*)g,
      (__attribute__((address_space(3))) unsigned int*)lds,
      16, 0, 0);
}

// ---------------------------------------------------------------- fused QKV NT GEMM
// r14: CAST KERNEL ELIMINATED — qkv reads fp32 sources directly and converts
// in-kernel. Reg-staging replaces global_load_lds: per iter, issue 8
// global dwordx4 (fp32 tile t+1) -> ds_read frags(t) + 16 MFMA (covers load
// latency; compiler places the waitcnt at the cvt) -> v_cvt_pk_bf16_f32 x16
// -> 4 ds_write_b128 into the OTHER buffer (byte-identical layout to the old
// async16 staging: granule s at (w*2+c)*1024 + lane*16, source col
// (c4 ^ ((row>>2)&3))*8) -> one __syncthreads -> swap. qkv had both pipes
// ~80% idle (r11-r13: MfmaUtil ~20, VALU ~20 across 3 schedule variants), so
// the conversion rides under existing stall time. 2 buffer-pairs, 32 KB LDS.
// Blocks >= 768 are a tail that casts Wo -> wob (bf16) for gemm_out: no
// separate cast launch. Bijective XCD swizzle for bid<768. r7 epilogue
// (swapped operands + LDS transpose + coalesced stores; z=2 folds pi32^-1).
__global__ __launch_bounds__(256) void qkv_gemm(
    const float* __restrict__ q,  const float* __restrict__ k,  const float* __restrict__ v,
    const float* __restrict__ Wq, const float* __restrict__ Wk, const float* __restrict__ Wv,
    const float* __restrict__ Wo,
    const float* __restrict__ bq, const float* __restrict__ bk, const float* __restrict__ bv,
    unsigned short* __restrict__ Qh, unsigned short* __restrict__ Kh,
    unsigned short* __restrict__ Vt, unsigned short* __restrict__ wob)
{
  const int bid = blockIdx.x;
  if (bid >= 768){
    // ---- tail: cast Wo (fp32) -> wob (bf16), coalesced 8 elems/thread x4
    int ibase = (bid - 768)*(256*32) + threadIdx.x*8;
    #pragma unroll
    for (int c = 0; c < 4; ++c){
      int i = ibase + c*2048;
      float4 a = *(const float4*)(Wo + i);
      float4 b = *(const float4*)(Wo + i + 4);
      uint4 o;
      o.x = cvt_pk_bf16(a.x, a.y); o.y = cvt_pk_bf16(a.z, a.w);
      o.z = cvt_pk_bf16(b.x, b.y); o.w = cvt_pk_bf16(b.z, b.w);
      *(uint4*)(wob + i) = o;
    }
    return;
  }

  __shared__ __align__(16) unsigned short S[128*128];   // 32 KB: 2 buffer-pairs
  const int id = (bid & 7) * 96 + (bid >> 3);           // XCD swizzle (bijective)
  const int z = id >> 8, r = id & 255;
  const float *A, *Bt; const float* bias; unsigned short* C;
  int bm, bn, N, brow; float scale;
  if (z == 0){ A = q;  Bt = Wq; bias = bq; C = Qh; bm = (r>>3)*128; bn = (r&7)*128; N = 1024; brow = 0; scale = SCALE_Q; }
  else if (z == 1){ A = k;  Bt = Wk; bias = bk; C = Kh; bm = (r>>3)*128; bn = (r&7)*128; N = 1024; brow = 0; scale = 1.0f; }
  else            { A = Wv; Bt = v;  bias = bv; C = Vt; bm = (r&7)*128; bn = (r>>3)*128; N = 4096; brow = 1; scale = 1.0f; }
  const int K = 1024;
  const int tid  = threadIdx.x, lane = tid & 63, w = tid >> 6;
  const int quad = lane >> 4,   l16  = lane & 15;
  const int wm = w >> 1, wn = w & 1;
  const int fsl = (quad ^ ((l16 >> 2) & 3)) << 3;       // fragment-read elem offset

  // per-thread staging sources (fp32; BK=32 tile = 512 granules, 2/thread/side)
  const float* asrc[2];
  const float* bsrc[2];
  int dsto[2];                                          // LDS byte offset in buffer
  #pragma unroll
  for (int c = 0; c < 2; ++c){
    int s = (w*2 + c)*64 + lane;
    int row = s >> 2, c4 = s & 3;
    int col = (c4 ^ ((row >> 2) & 3)) << 3;
    asrc[c] = A  + (size_t)(bm + row)*K + col;
    bsrc[c] = Bt + (size_t)(bn + row)*K + col;
    dsto[c] = (w*2 + c)*1024 + lane*16;
  }

  unsigned short *rdA = S,         *rdB = S + 4096;     // 8 KB each
  unsigned short *wrA = S + 8192,  *wrB = S + 12288;

  // ---- prologue: load + convert + write tile 0
  {
    #pragma unroll
    for (int c = 0; c < 2; ++c){
      float4 a0 = *(const float4*)asrc[c];
      float4 a1 = *(const float4*)(asrc[c] + 4);
      float4 b0 = *(const float4*)bsrc[c];
      float4 b1 = *(const float4*)(bsrc[c] + 4);
      asrc[c] += 32; bsrc[c] += 32;
      uint4 pa, pb;
      pa.x = cvt_pk_bf16(a0.x, a0.y); pa.y = cvt_pk_bf16(a0.z, a0.w);
      pa.z = cvt_pk_bf16(a1.x, a1.y); pa.w = cvt_pk_bf16(a1.z, a1.w);
      pb.x = cvt_pk_bf16(b0.x, b0.y); pb.y = cvt_pk_bf16(b0.z, b0.w);
      pb.z = cvt_pk_bf16(b1.x, b1.y); pb.w = cvt_pk_bf16(b1.z, b1.w);
      *(uint4*)((char*)rdA + dsto[c]) = pa;
      *(uint4*)((char*)rdB + dsto[c]) = pb;
    }
  }
  __syncthreads();

  f32x4 acc[4][4] = {};
  for (int t = 0; t < 31; ++t){
    // issue fp32 loads for tile t+1 (consumed after the MFMA cluster)
    float4 a00 = *(const float4*)asrc[0];
    float4 a01 = *(const float4*)(asrc[0] + 4);
    float4 a10 = *(const float4*)asrc[1];
    float4 a11 = *(const float4*)(asrc[1] + 4);
    float4 b00 = *(const float4*)bsrc[0];
    float4 b01 = *(const float4*)(bsrc[0] + 4);
    float4 b10 = *(const float4*)bsrc[1];
    float4 b11 = *(const float4*)(bsrc[1] + 4);
    asrc[0] += 32; asrc[1] += 32; bsrc[0] += 32; bsrc[1] += 32;

    // frags tile t + MFMA (reg/LDS only — overlaps the global-load latency)
    bf16x8 af[4], bf[4];
    #pragma unroll
    for (int mt = 0; mt < 4; ++mt){
      af[mt] = *(const bf16x8*)&rdA[(wm*64 + mt*16 + l16)*32 + fsl];
      bf[mt] = *(const bf16x8*)&rdB[(wn*64 + mt*16 + l16)*32 + fsl];
    }
    #pragma unroll
    for (int mt = 0; mt < 4; ++mt)
      #pragma unroll
      for (int nt = 0; nt < 4; ++nt)
        acc[mt][nt] = mfma16(bf[nt], af[mt], acc[mt][nt]);

    // convert + write tile t+1 into the buffer nobody is reading
    uint4 p;
    p.x = cvt_pk_bf16(a00.x, a00.y); p.y = cvt_pk_bf16(a00.z, a00.w);
    p.z = cvt_pk_bf16(a01.x, a01.y); p.w = cvt_pk_bf16(a01.z, a01.w);
    *(uint4*)((char*)wrA + dsto[0]) = p;
    p.x = cvt_pk_bf16(a10.x, a10.y); p.y = cvt_pk_bf16(a10.z, a10.w);
    p.z = cvt_pk_bf16(a11.x, a11.y); p.w = cvt_pk_bf16(a11.z, a11.w);
    *(uint4*)((char*)wrA + dsto[1]) = p;
    p.x = cvt_pk_bf16(b00.x, b00.y); p.y = cvt_pk_bf16(b00.z, b00.w);
    p.z = cvt_pk_bf16(b01.x, b01.y); p.w = cvt_pk_bf16(b01.z, b01.w);
    *(uint4*)((char*)wrB + dsto[0]) = p;
    p.x = cvt_pk_bf16(b10.x, b10.y); p.y = cvt_pk_bf16(b10.z, b10.w);
    p.z = cvt_pk_bf16(b11.x, b11.y); p.w = cvt_pk_bf16(b11.z, b11.w);
    *(uint4*)((char*)wrB + dsto[1]) = p;

    __syncthreads();                       // writes visible; reads of rd done
    unsigned short* tA = rdA; rdA = wrA; wrA = tA;
    unsigned short* tB = rdB; rdB = wrB; wrB = tB;
  }
  // final tile: frags + MFMA only
  {
    bf16x8 af[4], bf[4];
    #pragma unroll
    for (int mt = 0; mt < 4; ++mt){
      af[mt] = *(const bf16x8*)&rdA[(wm*64 + mt*16 + l16)*32 + fsl];
      bf[mt] = *(const bf16x8*)&rdB[(wn*64 + mt*16 + l16)*32 + fsl];
    }
    #pragma unroll
    for (int mt = 0; mt < 4; ++mt)
      #pragma unroll
      for (int nt = 0; nt < 4; ++nt)
        acc[mt][nt] = mfma16(bf[nt], af[mt], acc[mt][nt]);
  }
  __syncthreads();                         // all frag reads done; reuse S

  // ---- epilogue: pack + LDS transpose + coalesced dwordx4 stores
  #pragma unroll
  for (int nt = 0; nt < 4; ++nt){
    int nl = wn*64 + nt*16 + 4*quad;     // n base (step 4); rr spans nl..nl+3
    float4 b4;
    if (!brow) b4 = *(const float4*)&bias[bn + nl];
    #pragma unroll
    for (int mt = 0; mt < 4; ++mt){
      int ml = wm*64 + mt*16 + l16;      // m (0..127)
      float bmv = brow ? bias[bm + ml] : 0.0f;
      float v0 = (acc[mt][nt][0] + (brow ? bmv : b4.x)) * scale;
      float v1 = (acc[mt][nt][1] + (brow ? bmv : b4.y)) * scale;
      float v2 = (acc[mt][nt][2] + (brow ? bmv : b4.z)) * scale;
      float v3 = (acc[mt][nt][3] + (brow ? bmv : b4.w)) * scale;
      uint2 p2; p2.x = pack_bf2(v0, v1); p2.y = pack_bf2(v2, v3);
      int gl = nl >> 2;                  // 4-token granule 0..31
      if (brow){                         // fold pi32^-1 (maps 4-runs to 4-runs)
        int g3 = gl & 7;
        gl = (gl & ~7) | ((g3 & 3)*2 + (g3 >> 2));
      }
      int gs = gl ^ (ml & 14);           // even XOR key: write conflicts <=2-way
      *(uint2*)&S[ml*128 + gs*4] = p2;
    }
  }
  __syncthreads();
  {
    int rr_ = tid >> 1, hf = tid & 1;    // 2 threads per 128-col row
    size_t rowbase = (size_t)(bm + rr_) * N + bn;
    #pragma unroll
    for (int i = 0; i < 8; ++i){
      int gg = hf*16 + i*2;              // even granule pair
      uint4 d = *(const uint4*)&S[rr_*128 + ((gg ^ (rr_ & 14)) << 2)];
      *(uint4*)&C[rowbase + gg*4] = d;
    }
  }
}

// ---------------------------------------------------------------- out GEMM (fp32)
// (r9 version, unchanged) 64x128 tile, double-buffered BK=64 (48 KB LDS),
// vmcnt(6) + raw barrier skeleton, bijective XCD swizzle, 1D grid 512.
__global__ __launch_bounds__(256) void gemm_out(
    const unsigned short* __restrict__ A, const unsigned short* __restrict__ Bt,
    const float* __restrict__ bias, float* __restrict__ C)
{
  __shared__ __align__(16) unsigned short As[2][64*64];    // 8 KB each
  __shared__ __align__(16) unsigned short Bs[2][128*64];   // 16 KB each
  const int K = 1024, N = 1024;
  const int tid  = threadIdx.x, lane = tid & 63, w = tid >> 6;
  const int quad = lane >> 4,   l16  = lane & 15;
  int bid = blockIdx.x;                                    // XCD swizzle (bijective)
  const int id = (bid & 7) * 64 + (bid >> 3);
  const int bm = (id >> 3) * 64, bn = (id & 7) * 128;
  const int sw = l16 & 7;

  // per-thread staging sources (row&7 granule key, as before)
  const unsigned short* asrc[2];
  const unsigned short* bsrc[4];
  #pragma unroll
  for (int c = 0; c < 2; ++c){               // A: 512 chunks, 2/thread
    int chunk = (w*2 + c)*64 + lane;
    int row = chunk >> 3, c8 = chunk & 7;
    asrc[c] = A + (size_t)(bm + row)*K + ((c8 ^ (row & 7)) << 3);
  }
  #pragma unroll
  for (int c = 0; c < 4; ++c){               // B: 1024 chunks, 4/thread
    int chunk = (w*4 + c)*64 + lane;
    int row = chunk >> 3, c8 = chunk & 7;
    bsrc[c] = Bt + (size_t)(bn + row)*K + ((c8 ^ (row & 7)) << 3);
  }

  // ---- stage k-tile 0 into buf0
  #pragma unroll
  for (int c = 0; c < 2; ++c){ async16(asrc[c], (char*)As[0] + (w*2 + c)*1024); asrc[c] += 64; }
  #pragma unroll
  for (int c = 0; c < 4; ++c){ async16(bsrc[c], (char*)Bs[0] + (w*4 + c)*1024); bsrc[c] += 64; }

  f32x4 acc[4][2] = {};
  for (int t = 0; t < 16; ++t){
    const int cur = t & 1;
    #pragma unroll
    for (int c = 0; c < 2; ++c){            // prefetch tile t+1 (t=15: garbage, in pad)
      async16(asrc[c], (char*)As[1 - cur] + (w*2 + c)*1024); asrc[c] += 64;
    }
    #pragma unroll
    for (int c = 0; c < 4; ++c){
      async16(bsrc[c], (char*)Bs[1 - cur] + (w*4 + c)*1024); bsrc[c] += 64;
    }
    // wait only for CURRENT tile's 6 loads; next tile's 6 stay in flight.
    asm volatile("s_waitcnt vmcnt(6)\n\ts_barrier" ::: "memory");

    const unsigned short* Ac = As[cur];
    bf16x8 af[4][2], bf[2][2];
    #pragma unroll
    for (int mt = 0; mt < 4; ++mt)
      #pragma unroll
      for (int ks = 0; ks < 2; ++ks)
        af[mt][ks] = *(const bf16x8*)&Ac[(mt*16 + l16)*64 + (((ks*4 + quad) ^ sw) << 3)];
    #pragma unroll
    for (int nt = 0; nt < 2; ++nt)
      #pragma unroll
      for (int ks = 0; ks < 2; ++ks)
        bf[nt][ks] = *(const bf16x8*)&Bs[cur][(w*32 + nt*16 + l16)*64 + (((ks*4 + quad) ^ sw) << 3)];
    #pragma unroll
    for (int ks = 0; ks < 2; ++ks)
      #pragma unroll
      for (int mt = 0; mt < 4; ++mt)
        #pragma unroll
        for (int nt = 0; nt < 2; ++nt)
          acc[mt][nt] = mfma16(af[mt][ks], bf[nt][ks], acc[mt][nt]);

    // my frag reads from buf[cur] retired -> safe to restage it next iter.
    asm volatile("s_waitcnt lgkmcnt(0)\n\ts_barrier" ::: "memory");
  }

  #pragma unroll
  for (int mt = 0; mt < 4; ++mt){
    #pragma unroll
    for (int nt = 0; nt < 2; ++nt){
      int col = bn + w*32 + nt*16 + l16;
      float bc = bias[col];
      #pragma unroll
      for (int rr = 0; rr < 4; ++rr){
        int row = bm + mt*16 + quad*4 + rr;
        C[(size_t)row*N + col] = acc[mt][nt][rr] + bc;
      }
    }
  }
}

// ---------------------------------------------------------------- flash attention
// (r10 version, unchanged — best measured: 45.9 us, occ 35%).
// grid (SS/128, B*H), 512 threads = 8 waves x 16 q of the same 128-q tile;
// staging per block unchanged (1 K + 1 V granule/thread, vmcnt(2));
// 2 blocks x 8 waves = 16 waves/CU. P in registers (pi-permuted PV, r3);
// V as conflict-free contiguous b128 (Vt pre-permuted by pi32^-1, r6).
__global__ __launch_bounds__(512, 4) void attn(
    const unsigned short* __restrict__ Qh, const unsigned short* __restrict__ Kh,
    const unsigned short* __restrict__ Vt, unsigned short* __restrict__ ctx)
{
  __shared__ __align__(16) unsigned short Kbuf[2][64*64];
  __shared__ __align__(16) unsigned short Vbuf[2][64*64];
  __shared__ __align__(16) unsigned short QP[128*64];   // Q tile, then O

  const int tid  = threadIdx.x, lane = tid & 63, w = tid >> 6;   // w: 0..7
  const int quad = lane >> 4,   l16  = lane & 15;
  const int b = blockIdx.y >> 4, h = blockIdx.y & 15;
  const int q0 = blockIdx.x * 128;
  const int sw = l16 & 7;                    // read-side swizzle key (row&7 == l16&7)

  // ---- stage Q tile [128 q][64 dk], swizzled: 1024 granules, 2/thread
  #pragma unroll
  for (int c = 0; c < 2; ++c){
    int s = (w*2 + c)*64 + lane;
    int row = s >> 3, c8 = s & 7;
    async16(Qh + (size_t)(b*SS + q0 + row)*D_MODEL + h*DK + ((c8 ^ (row & 7)) << 3),
            (char*)QP + (w*2 + c)*1024);
  }

  // per-thread staging sources for K and V (1 granule each; bump per stage)
  const unsigned short* ksrc;
  const unsigned short* vsrc;
  {
    const unsigned short* Kpp = Kh + (size_t)(b*SS)*D_MODEL + h*DK;
    const unsigned short* Vpp = Vt + (size_t)(h*DK)*NTOK + b*SS;
    int s = w*64 + lane;                     // 0..511 granules
    int row = s >> 3, c8 = s & 7;
    int cs = (c8 ^ (row & 7)) << 3;
    ksrc = Kpp + (size_t)row*D_MODEL + cs;
    vsrc = Vpp + (size_t)row*NTOK  + cs;
  }

  // ---- stage kv tile 0 into buf0
  async16(ksrc, (char*)Kbuf[0] + w*1024);
  async16(vsrc, (char*)Vbuf[0] + w*1024);
  ksrc += 64*D_MODEL;
  vsrc += 64;
  __syncthreads();                           // one-time full drain (Q + tile0)

  bf16x8 bq[2];                              // B-operand = this wave's 16 Q rows
  #pragma unroll
  for (int ks = 0; ks < 2; ++ks)
    bq[ks] = *(const bf16x8*)&QP[(w*16 + l16)*64 + (((ks*4 + quad) ^ sw) << 3)];

  f32x4 acc[4] = {};                         // O^T: [dk-tile], col=q, row=dk
  float l0a = 0.0f, l0b = 0.0f;

  for (int it = 0; it < 32; ++it){
    const int cur = it & 1;
    // prefetch next tile into the other buffer (it=31: garbage prefetch, in-ws)
    async16(ksrc, (char*)Kbuf[1 - cur] + w*1024);
    async16(vsrc, (char*)Vbuf[1 - cur] + w*1024);
    ksrc += 64*D_MODEL;
    vsrc += 64;
    // wait only for CURRENT tile's 2 loads (issued a full compute phase ago);
    // next tile's 2 stay in flight. Raw barrier: no vmcnt(0) drain.
    asm volatile("s_waitcnt vmcnt(2)\n\ts_barrier" ::: "memory");

    const unsigned short* Kc = Kbuf[cur];
    const unsigned short* Vc = Vbuf[cur];

    // K fragments (full 64 kv rows)
    bf16x8 kf[4][2];
    #pragma unroll
    for (int mt = 0; mt < 4; ++mt)
      #pragma unroll
      for (int ks = 0; ks < 2; ++ks)
        kf[mt][ks] = *(const bf16x8*)&Kc[(mt*16 + l16)*64 + (((ks*4 + quad) ^ sw) << 3)];

    // V fragments: contiguous b128, conflict-free (Vt pre-permuted by pi32^-1)
    bf16x8 vf[4][2];
    #pragma unroll
    for (int nt = 0; nt < 4; ++nt)
      #pragma unroll
      for (int ks = 0; ks < 2; ++ks)
        vf[nt][ks] = *(const bf16x8*)&Vc[(nt*16 + l16)*64 + (((ks*4 + quad) ^ sw) << 3)];

    // S^T = K.Q^T for this wave's 16 q
    f32x4 s0[4] = {};
    #pragma unroll
    for (int mt = 0; mt < 4; ++mt)
      #pragma unroll
      for (int ks = 0; ks < 2; ++ks)
        s0[mt] = mfma16(kf[mt][ks], bq[ks], s0[mt]);

    // softmax (no max subtraction), two partial sums
    float sa = 0.0f, sb = 0.0f;
    #pragma unroll
    for (int mt = 0; mt < 4; ++mt)
      #pragma unroll
      for (int rr = 0; rr < 4; ++rr){
        float p0 = fast_exp2(s0[mt][rr]); s0[mt][rr] = p0;
        if (mt & 1) sb += p0; else sa += p0;
      }
    l0a += sa; l0b += sb;

    // in-register P -> bf16 B-fragments (natural register order under pi)
    bf16x8 bp[2];
    #pragma unroll
    for (int ks = 0; ks < 2; ++ks){
      uint4 t;
      t.x = cvt_pk_bf16(s0[2*ks  ][0], s0[2*ks  ][1]);
      t.y = cvt_pk_bf16(s0[2*ks  ][2], s0[2*ks  ][3]);
      t.z = cvt_pk_bf16(s0[2*ks+1][0], s0[2*ks+1][1]);
      t.w = cvt_pk_bf16(s0[2*ks+1][2], s0[2*ks+1][3]);
      bp[ks] = __builtin_bit_cast(bf16x8, t);
    }

    // O^T += V^T.P^T (k-permuted on both sides)
    #pragma unroll
    for (int nt = 0; nt < 4; ++nt)
      #pragma unroll
      for (int ks = 0; ks < 2; ++ks)
        acc[nt] = mfma16(vf[nt][ks], bp[ks], acc[nt]);

    // all my LDS reads from buf[cur] retired -> safe for others to restage it.
    asm volatile("s_waitcnt lgkmcnt(0)\n\ts_barrier" ::: "memory");
  }

  // ---- epilogue: normalize, O^T -> QP (wave-private rows), transpose out
  float t = l0a + l0b;
  t += __shfl_xor(t, 16);
  t += __shfl_xor(t, 32);
  const float inv = 1.0f / t;

  {
    const int pr = (w*16 + l16)*64;
    #pragma unroll
    for (int nt = 0; nt < 4; ++nt){
      int c8  = nt*2 + (quad >> 1);
      int off = ((c8 ^ sw) << 3) + (quad & 1)*4;
      uint2 p;
      p.x = pack_bf2(acc[nt][0]*inv, acc[nt][1]*inv);
      p.y = pack_bf2(acc[nt][2]*inv, acc[nt][3]*inv);
      *(uint2*)&QP[pr + off] = p;
    }
  }
  asm volatile("s_waitcnt lgkmcnt(0)" ::: "memory");
  {
    int r  = w*16 + (lane >> 2);             // wave-private rows: no barrier needed
    int j0 = lane & 3;
    unsigned short* dst = ctx + (size_t)(b*SS + q0 + r)*D_MODEL + h*DK;
    #pragma unroll
    for (int i = 0; i < 2; ++i){
      int j = j0 + i*4;
      uint4 d = *(const uint4*)&QP[r*64 + ((j ^ (r & 7)) << 3)];
      *(uint4*)(dst + j*8) = d;
    }
  }
}

// ---------------------------------------------------------------- launch
extern "C" void kernel_launch(void* const* d_in, const int* in_sizes, int n_in,
                              void* d_out, int out_size, void* d_ws, size_t ws_size,
                              hipStream_t stream) {
  const float* q  = (const float*)d_in[0];
  const float* k  = (const float*)d_in[1];
  const float* v  = (const float*)d_in[2];
  const float* Wq = (const float*)d_in[3];
  const float* bq = (const float*)d_in[4];
  const float* Wk = (const float*)d_in[5];
  const float* bk = (const float*)d_in[6];
  const float* Wv = (const float*)d_in[7];
  const float* bv = (const float*)d_in[8];
  const float* Wo = (const float*)d_in[9];
  const float* bo = (const float*)d_in[10];

  char* ws = (char*)d_ws;
  const size_t TOKB = (size_t)NTOK * D_MODEL * 2;     // 8 MB
  const size_t WB   = (size_t)D_MODEL * D_MODEL * 2;  // 2 MB
  unsigned short* wob = (unsigned short*)ws;             ws += WB;
  unsigned short* Qh  = (unsigned short*)ws;             ws += TOKB;  // [4096][1024], pre-scaled
  unsigned short* Kh  = (unsigned short*)ws;             ws += TOKB;  // [4096][1024]
  unsigned short* Vt  = (unsigned short*)ws;             ws += TOKB;  // [1024][4096], pi-permuted cols
  unsigned short* ctx = (unsigned short*)ws;             ws += TOKB;  // [4096][1024]
  ws += 4096;   // pad: gemm_out's t=15 garbage prefetch reads <=128B past ctx

  // cast kernel ELIMINATED: qkv_gemm reads fp32 directly (reg-stage + cvt_pk);
  // its 128 tail blocks cast Wo -> wob for gemm_out.
  qkv_gemm<<<dim3(896), 256, 0, stream>>>(q, k, v, Wq, Wk, Wv, Wo,
                                          bq, bk, bv, Qh, Kh, Vt, wob);
  attn<<<dim3(SS/128, BB*NHEAD), 512, 0, stream>>>(Qh, Kh, Vt, ctx);
  gemm_out<<<dim3(512), 256, 0, stream>>>(ctx, wob, bo, (float*)d_out);
}

// Round 15
// 212.403 us; speedup vs baseline: 1.1386x; 1.1386x over previous
//
#include <hip/hip_runtime.h>
#include <stdint.h>
#include <stddef.h>

#define D_MODEL 1024
#define NHEAD   16
#define DK      64
#define BB      2
#define SS      2048
#define NTOK    (BB*SS)   // 4096

// log2(e) / sqrt(Dk) folded into the Q projection output:
#define SCALE_Q 0.18033688011f

typedef short  short8 __attribute__((ext_vector_type(8)));
typedef __bf16 bf16x8 __attribute__((ext_vector_type(8)));
typedef float  f32x4  __attribute__((ext_vector_type(4)));

__device__ __forceinline__ unsigned short f2bf(float x){   // RNE (cast path)
  unsigned int u = __builtin_bit_cast(unsigned int, x);
  u += 0x7fffu + ((u >> 16) & 1u);
  return (unsigned short)(u >> 16);
}

// pack two f32 -> two bf16 (round-half-up) in 3 VALU: add, add, v_perm
__device__ __forceinline__ unsigned int pack_bf2(float x, float y){
  unsigned int a = __builtin_bit_cast(unsigned int, x) + 0x8000u;
  unsigned int b = __builtin_bit_cast(unsigned int, y) + 0x8000u;
  return __builtin_amdgcn_perm(b, a, 0x07060302u);  // [y_hi16 | x_hi16]
}

// two f32 -> packed bf16x2 in ONE VALU (RNE). dst.lo = lo, dst.hi = hi.
__device__ __forceinline__ unsigned int cvt_pk_bf16(float lo, float hi){
  unsigned int r;
  asm("v_cvt_pk_bf16_f32 %0, %1, %2" : "=v"(r) : "v"(lo), "v"(hi));
  return r;
}

__device__ __forceinline__ float fast_exp2(float x){
#if __has_builtin(__builtin_amdgcn_exp2f)
  return __builtin_amdgcn_exp2f(x);   // raw v_exp_f32; args bounded, no denorms
#else
  return exp2f(x);
#endif
}

__device__ __forceinline__ f32x4 mfma16(bf16x8 a, bf16x8 b, f32x4 c){
  return __builtin_amdgcn_mfma_f32_16x16x32_bf16(a, b, c, 0, 0, 0);
}

// async global->LDS, 16B/lane; LDS dst = wave-uniform base + lane*16
__device__ __forceinline__ void async16(const void* g, void* lds){
  __builtin_amdgcn_global_load_lds(
      (const __attribute__((address_space(1))) unsigned int*)g,
      (__attribute__((address_space(3))) unsigned int*)lds,
      16, 0, 0);
}

// ---------------------------------------------------------------- cast fp32->bf16
__global__ __launch_bounds__(256) void cast_bf16_all(
    const float* __restrict__ q,  const float* __restrict__ k,  const float* __restrict__ v,
    const float* __restrict__ wq, const float* __restrict__ wk, const float* __restrict__ wv,
    const float* __restrict__ wo,
    unsigned short* __restrict__ qb,  unsigned short* __restrict__ kb,  unsigned short* __restrict__ vb,
    unsigned short* __restrict__ wqb, unsigned short* __restrict__ wkb, unsigned short* __restrict__ wvb,
    unsigned short* __restrict__ wob)
{
  const float* src; unsigned short* dst; int n;
  switch (blockIdx.y){
    case 0: src = q;  dst = qb;  n = NTOK*D_MODEL;    break;
    case 1: src = k;  dst = kb;  n = NTOK*D_MODEL;    break;
    case 2: src = v;  dst = vb;  n = NTOK*D_MODEL;    break;
    case 3: src = wq; dst = wqb; n = D_MODEL*D_MODEL; break;
    case 4: src = wk; dst = wkb; n = D_MODEL*D_MODEL; break;
    case 5: src = wv; dst = wvb; n = D_MODEL*D_MODEL; break;
    default: src = wo; dst = wob; n = D_MODEL*D_MODEL; break;
  }
  int i = (blockIdx.x * 256 + threadIdx.x) * 8;
  if (i >= n) return;
  float4 a = *(const float4*)(src + i);
  float4 b = *(const float4*)(src + i + 4);
  short8 o;
  o[0] = (short)f2bf(a.x); o[1] = (short)f2bf(a.y);
  o[2] = (short)f2bf(a.z); o[3] = (short)f2bf(a.w);
  o[4] = (short)f2bf(b.x); o[5] = (short)f2bf(b.y);
  o[6] = (short)f2bf(b.z); o[7] = (short)f2bf(b.w);
  *(short8*)(dst + i) = o;
}

// ---------------------------------------------------------------- fused QKV NT GEMM
// (r8 version — best measured) z=0: Qh=(qb.Wq^T+bq)*SCALE_Q; z=1: Kh=kb.Wk^T+bk;
// z=2: Vt=Wv.vb^T+bv. 128x128 tile, DOUBLE-BUFFERED BK=32 K-loop in 32 KB LDS:
// issue stage(t+1) -> vmcnt(4) + raw s_barrier -> 8 ds_read_b128 -> 16 MFMA ->
// lgkmcnt(0) + raw s_barrier. Bijective XCD swizzle. r7 epilogue (swapped
// operands + LDS transpose + coalesced stores; z=2 folds pi32^-1).
__global__ __launch_bounds__(256) void qkv_gemm(
    const unsigned short* __restrict__ qb, const unsigned short* __restrict__ kb,
    const unsigned short* __restrict__ vb,
    const unsigned short* __restrict__ wqb, const unsigned short* __restrict__ wkb,
    const unsigned short* __restrict__ wvb,
    const float* __restrict__ bq, const float* __restrict__ bk, const float* __restrict__ bv,
    unsigned short* __restrict__ Qh, unsigned short* __restrict__ Kh, unsigned short* __restrict__ Vt)
{
  __shared__ __align__(16) unsigned short S[128*128];   // 32 KB total
  unsigned short* As0 = S;                              // [128 m][32 k] 8 KB
  unsigned short* Bs0 = S + 4096;
  unsigned short* As1 = S + 8192;
  unsigned short* Bs1 = S + 12288;

  int bid = blockIdx.x;                                 // XCD swizzle (bijective)
  const int id = (bid & 7) * 96 + (bid >> 3);
  const int z = id >> 8, r = id & 255;
  const unsigned short *A, *Bt; const float* bias; unsigned short* C;
  int bm, bn, N, brow; float scale;
  if (z == 0){ A = qb;  Bt = wqb; bias = bq; C = Qh; bm = (r>>3)*128; bn = (r&7)*128; N = 1024; brow = 0; scale = SCALE_Q; }
  else if (z == 1){ A = kb;  Bt = wkb; bias = bk; C = Kh; bm = (r>>3)*128; bn = (r&7)*128; N = 1024; brow = 0; scale = 1.0f; }
  else            { A = wvb; Bt = vb;  bias = bv; C = Vt; bm = (r&7)*128; bn = (r>>3)*128; N = 4096; brow = 1; scale = 1.0f; }
  const int K = 1024;
  const int tid  = threadIdx.x, lane = tid & 63, w = tid >> 6;
  const int quad = lane >> 4,   l16  = lane & 15;
  const int wm = w >> 1, wn = w & 1;
  const int fsl = (quad ^ ((l16 >> 2) & 3)) << 3;       // fragment-read elem offset

  // per-thread staging sources (BK=32 tile: 512 granules, 2/thread each side)
  const unsigned short* asrc[2];
  const unsigned short* bsrc[2];
  #pragma unroll
  for (int c = 0; c < 2; ++c){
    int s = (w*2 + c)*64 + lane;
    int row = s >> 2, c4 = s & 3;
    int cs = (c4 ^ ((row >> 2) & 3)) << 3;
    asrc[c] = A  + (size_t)(bm + row)*K + cs;
    bsrc[c] = Bt + (size_t)(bn + row)*K + cs;
  }

  // ---- stage k-tile 0 into buf0
  #pragma unroll
  for (int c = 0; c < 2; ++c){
    async16(asrc[c], (char*)As0 + (w*2 + c)*1024);
    async16(bsrc[c], (char*)Bs0 + (w*2 + c)*1024);
    asrc[c] += 32; bsrc[c] += 32;
  }

  f32x4 acc[4][4] = {};
  for (int t = 0; t < 32; ++t){
    const int cur = t & 1;
    unsigned short* An = cur ? As0 : As1;   // next buffer
    unsigned short* Bn = cur ? Bs0 : Bs1;
    #pragma unroll
    for (int c = 0; c < 2; ++c){            // prefetch tile t+1 (t=31: garbage, in-ws)
      async16(asrc[c], (char*)An + (w*2 + c)*1024);
      async16(bsrc[c], (char*)Bn + (w*2 + c)*1024);
      asrc[c] += 32; bsrc[c] += 32;
    }
    // wait only for CURRENT tile's 4 loads; next tile's 4 stay in flight.
    asm volatile("s_waitcnt vmcnt(4)\n\ts_barrier" ::: "memory");

    const unsigned short* Ac = cur ? As1 : As0;
    const unsigned short* Bc = cur ? Bs1 : Bs0;
    bf16x8 af[4], bf[4];
    #pragma unroll
    for (int mt = 0; mt < 4; ++mt){
      af[mt] = *(const bf16x8*)&Ac[(wm*64 + mt*16 + l16)*32 + fsl];
      bf[mt] = *(const bf16x8*)&Bc[(wn*64 + mt*16 + l16)*32 + fsl];
    }
    // SWAPPED operand order: output col = l16 = m, rows = n (4quad+rr).
    #pragma unroll
    for (int mt = 0; mt < 4; ++mt)
      #pragma unroll
      for (int nt = 0; nt < 4; ++nt)
        acc[mt][nt] = mfma16(bf[nt], af[mt], acc[mt][nt]);

    // my frag reads from buf[cur] retired -> safe to restage it next iter.
    asm volatile("s_waitcnt lgkmcnt(0)\n\ts_barrier" ::: "memory");
  }
  // garbage tile-32 DMA may still target As0/Bs0 (= S): drain before reuse.
  asm volatile("s_waitcnt vmcnt(0)\n\ts_barrier" ::: "memory");

  // ---- epilogue: pack + LDS transpose + coalesced dwordx4 stores
  #pragma unroll
  for (int nt = 0; nt < 4; ++nt){
    int nl = wn*64 + nt*16 + 4*quad;     // n base (step 4); rr spans nl..nl+3
    float4 b4;
    if (!brow) b4 = *(const float4*)&bias[bn + nl];
    #pragma unroll
    for (int mt = 0; mt < 4; ++mt){
      int ml = wm*64 + mt*16 + l16;      // m (0..127)
      float bmv = brow ? bias[bm + ml] : 0.0f;
      float v0 = (acc[mt][nt][0] + (brow ? bmv : b4.x)) * scale;
      float v1 = (acc[mt][nt][1] + (brow ? bmv : b4.y)) * scale;
      float v2 = (acc[mt][nt][2] + (brow ? bmv : b4.z)) * scale;
      float v3 = (acc[mt][nt][3] + (brow ? bmv : b4.w)) * scale;
      uint2 p; p.x = pack_bf2(v0, v1); p.y = pack_bf2(v2, v3);
      int gl = nl >> 2;                  // 4-token granule 0..31
      if (brow){                         // fold pi32^-1 (maps 4-runs to 4-runs)
        int g3 = gl & 7;
        gl = (gl & ~7) | ((g3 & 3)*2 + (g3 >> 2));
      }
      int gs = gl ^ (ml & 14);           // even XOR key: write conflicts <=2-way
      *(uint2*)&S[ml*128 + gs*4] = p;
    }
  }
  __syncthreads();
  {
    int rr_ = tid >> 1, hf = tid & 1;    // 2 threads per 128-col row
    size_t rowbase = (size_t)(bm + rr_) * N + bn;
    #pragma unroll
    for (int i = 0; i < 8; ++i){
      int gg = hf*16 + i*2;              // even granule pair
      uint4 d = *(const uint4*)&S[rr_*128 + ((gg ^ (rr_ & 14)) << 2)];
      *(uint4*)&C[rowbase + gg*4] = d;
    }
  }
}

// ---------------------------------------------------------------- out GEMM (fp32)
// (r9 version) 64x128 tile, double-buffered BK=64 (48 KB LDS),
// vmcnt(6) + raw barrier skeleton, bijective XCD swizzle, 1D grid 512.
__global__ __launch_bounds__(256) void gemm_out(
    const unsigned short* __restrict__ A, const unsigned short* __restrict__ Bt,
    const float* __restrict__ bias, float* __restrict__ C)
{
  __shared__ __align__(16) unsigned short As[2][64*64];    // 8 KB each
  __shared__ __align__(16) unsigned short Bs[2][128*64];   // 16 KB each
  const int K = 1024, N = 1024;
  const int tid  = threadIdx.x, lane = tid & 63, w = tid >> 6;
  const int quad = lane >> 4,   l16  = lane & 15;
  int bid = blockIdx.x;                                    // XCD swizzle (bijective)
  const int id = (bid & 7) * 64 + (bid >> 3);
  const int bm = (id >> 3) * 64, bn = (id & 7) * 128;
  const int sw = l16 & 7;

  // per-thread staging sources (row&7 granule key, as before)
  const unsigned short* asrc[2];
  const unsigned short* bsrc[4];
  #pragma unroll
  for (int c = 0; c < 2; ++c){               // A: 512 chunks, 2/thread
    int chunk = (w*2 + c)*64 + lane;
    int row = chunk >> 3, c8 = chunk & 7;
    asrc[c] = A + (size_t)(bm + row)*K + ((c8 ^ (row & 7)) << 3);
  }
  #pragma unroll
  for (int c = 0; c < 4; ++c){               // B: 1024 chunks, 4/thread
    int chunk = (w*4 + c)*64 + lane;
    int row = chunk >> 3, c8 = chunk & 7;
    bsrc[c] = Bt + (size_t)(bn + row)*K + ((c8 ^ (row & 7)) << 3);
  }

  // ---- stage k-tile 0 into buf0
  #pragma unroll
  for (int c = 0; c < 2; ++c){ async16(asrc[c], (char*)As[0] + (w*2 + c)*1024); asrc[c] += 64; }
  #pragma unroll
  for (int c = 0; c < 4; ++c){ async16(bsrc[c], (char*)Bs[0] + (w*4 + c)*1024); bsrc[c] += 64; }

  f32x4 acc[4][2] = {};
  for (int t = 0; t < 16; ++t){
    const int cur = t & 1;
    #pragma unroll
    for (int c = 0; c < 2; ++c){            // prefetch tile t+1 (t=15: garbage, in pad)
      async16(asrc[c], (char*)As[1 - cur] + (w*2 + c)*1024); asrc[c] += 64;
    }
    #pragma unroll
    for (int c = 0; c < 4; ++c){
      async16(bsrc[c], (char*)Bs[1 - cur] + (w*4 + c)*1024); bsrc[c] += 64;
    }
    // wait only for CURRENT tile's 6 loads; next tile's 6 stay in flight.
    asm volatile("s_waitcnt vmcnt(6)\n\ts_barrier" ::: "memory");

    const unsigned short* Ac = As[cur];
    bf16x8 af[4][2], bf[2][2];
    #pragma unroll
    for (int mt = 0; mt < 4; ++mt)
      #pragma unroll
      for (int ks = 0; ks < 2; ++ks)
        af[mt][ks] = *(const bf16x8*)&Ac[(mt*16 + l16)*64 + (((ks*4 + quad) ^ sw) << 3)];
    #pragma unroll
    for (int nt = 0; nt < 2; ++nt)
      #pragma unroll
      for (int ks = 0; ks < 2; ++ks)
        bf[nt][ks] = *(const bf16x8*)&Bs[cur][(w*32 + nt*16 + l16)*64 + (((ks*4 + quad) ^ sw) << 3)];
    #pragma unroll
    for (int ks = 0; ks < 2; ++ks)
      #pragma unroll
      for (int mt = 0; mt < 4; ++mt)
        #pragma unroll
        for (int nt = 0; nt < 2; ++nt)
          acc[mt][nt] = mfma16(af[mt][ks], bf[nt][ks], acc[mt][nt]);

    // my frag reads from buf[cur] retired -> safe to restage it next iter.
    asm volatile("s_waitcnt lgkmcnt(0)\n\ts_barrier" ::: "memory");
  }

  #pragma unroll
  for (int mt = 0; mt < 4; ++mt){
    #pragma unroll
    for (int nt = 0; nt < 2; ++nt){
      int col = bn + w*32 + nt*16 + l16;
      float bc = bias[col];
      #pragma unroll
      for (int rr = 0; rr < 4; ++rr){
        int row = bm + mt*16 + quad*4 + rr;
        C[(size_t)row*N + col] = acc[mt][nt][rr] + bc;
      }
    }
  }
}

// ---------------------------------------------------------------- flash attention
// (r10 version — best measured: 45.9 us, occ 35%).
// grid (SS/128, B*H), 512 threads = 8 waves x 16 q of the same 128-q tile;
// staging per block unchanged (1 K + 1 V granule/thread, vmcnt(2));
// 2 blocks x 8 waves = 16 waves/CU. P in registers (pi-permuted PV, r3);
// V as conflict-free contiguous b128 (Vt pre-permuted by pi32^-1, r6).
__global__ __launch_bounds__(512, 4) void attn(
    const unsigned short* __restrict__ Qh, const unsigned short* __restrict__ Kh,
    const unsigned short* __restrict__ Vt, unsigned short* __restrict__ ctx)
{
  __shared__ __align__(16) unsigned short Kbuf[2][64*64];
  __shared__ __align__(16) unsigned short Vbuf[2][64*64];
  __shared__ __align__(16) unsigned short QP[128*64];   // Q tile, then O

  const int tid  = threadIdx.x, lane = tid & 63, w = tid >> 6;   // w: 0..7
  const int quad = lane >> 4,   l16  = lane & 15;
  const int b = blockIdx.y >> 4, h = blockIdx.y & 15;
  const int q0 = blockIdx.x * 128;
  const int sw = l16 & 7;                    // read-side swizzle key (row&7 == l16&7)

  // ---- stage Q tile [128 q][64 dk], swizzled: 1024 granules, 2/thread
  #pragma unroll
  for (int c = 0; c < 2; ++c){
    int s = (w*2 + c)*64 + lane;
    int row = s >> 3, c8 = s & 7;
    async16(Qh + (size_t)(b*SS + q0 + row)*D_MODEL + h*DK + ((c8 ^ (row & 7)) << 3),
            (char*)QP + (w*2 + c)*1024);
  }

  // per-thread staging sources for K and V (1 granule each; bump per stage)
  const unsigned short* ksrc;
  const unsigned short* vsrc;
  {
    const unsigned short* Kpp = Kh + (size_t)(b*SS)*D_MODEL + h*DK;
    const unsigned short* Vpp = Vt + (size_t)(h*DK)*NTOK + b*SS;
    int s = w*64 + lane;                     // 0..511 granules
    int row = s >> 3, c8 = s & 7;
    int cs = (c8 ^ (row & 7)) << 3;
    ksrc = Kpp + (size_t)row*D_MODEL + cs;
    vsrc = Vpp + (size_t)row*NTOK  + cs;
  }

  // ---- stage kv tile 0 into buf0
  async16(ksrc, (char*)Kbuf[0] + w*1024);
  async16(vsrc, (char*)Vbuf[0] + w*1024);
  ksrc += 64*D_MODEL;
  vsrc += 64;
  __syncthreads();                           // one-time full drain (Q + tile0)

  bf16x8 bq[2];                              // B-operand = this wave's 16 Q rows
  #pragma unroll
  for (int ks = 0; ks < 2; ++ks)
    bq[ks] = *(const bf16x8*)&QP[(w*16 + l16)*64 + (((ks*4 + quad) ^ sw) << 3)];

  f32x4 acc[4] = {};                         // O^T: [dk-tile], col=q, row=dk
  float l0a = 0.0f, l0b = 0.0f;

  for (int it = 0; it < 32; ++it){
    const int cur = it & 1;
    // prefetch next tile into the other buffer (it=31: garbage prefetch, in-ws)
    async16(ksrc, (char*)Kbuf[1 - cur] + w*1024);
    async16(vsrc, (char*)Vbuf[1 - cur] + w*1024);
    ksrc += 64*D_MODEL;
    vsrc += 64;
    // wait only for CURRENT tile's 2 loads (issued a full compute phase ago);
    // next tile's 2 stay in flight. Raw barrier: no vmcnt(0) drain.
    asm volatile("s_waitcnt vmcnt(2)\n\ts_barrier" ::: "memory");

    const unsigned short* Kc = Kbuf[cur];
    const unsigned short* Vc = Vbuf[cur];

    // K fragments (full 64 kv rows)
    bf16x8 kf[4][2];
    #pragma unroll
    for (int mt = 0; mt < 4; ++mt)
      #pragma unroll
      for (int ks = 0; ks < 2; ++ks)
        kf[mt][ks] = *(const bf16x8*)&Kc[(mt*16 + l16)*64 + (((ks*4 + quad) ^ sw) << 3)];

    // V fragments: contiguous b128, conflict-free (Vt pre-permuted by pi32^-1)
    bf16x8 vf[4][2];
    #pragma unroll
    for (int nt = 0; nt < 4; ++nt)
      #pragma unroll
      for (int ks = 0; ks < 2; ++ks)
        vf[nt][ks] = *(const bf16x8*)&Vc[(nt*16 + l16)*64 + (((ks*4 + quad) ^ sw) << 3)];

    // S^T = K.Q^T for this wave's 16 q
    f32x4 s0[4] = {};
    #pragma unroll
    for (int mt = 0; mt < 4; ++mt)
      #pragma unroll
      for (int ks = 0; ks < 2; ++ks)
        s0[mt] = mfma16(kf[mt][ks], bq[ks], s0[mt]);

    // softmax (no max subtraction), two partial sums
    float sa = 0.0f, sb = 0.0f;
    #pragma unroll
    for (int mt = 0; mt < 4; ++mt)
      #pragma unroll
      for (int rr = 0; rr < 4; ++rr){
        float p0 = fast_exp2(s0[mt][rr]); s0[mt][rr] = p0;
        if (mt & 1) sb += p0; else sa += p0;
      }
    l0a += sa; l0b += sb;

    // in-register P -> bf16 B-fragments (natural register order under pi)
    bf16x8 bp[2];
    #pragma unroll
    for (int ks = 0; ks < 2; ++ks){
      uint4 t;
      t.x = cvt_pk_bf16(s0[2*ks  ][0], s0[2*ks  ][1]);
      t.y = cvt_pk_bf16(s0[2*ks  ][2], s0[2*ks  ][3]);
      t.z = cvt_pk_bf16(s0[2*ks+1][0], s0[2*ks+1][1]);
      t.w = cvt_pk_bf16(s0[2*ks+1][2], s0[2*ks+1][3]);
      bp[ks] = __builtin_bit_cast(bf16x8, t);
    }

    // O^T += V^T.P^T (k-permuted on both sides)
    #pragma unroll
    for (int nt = 0; nt < 4; ++nt)
      #pragma unroll
      for (int ks = 0; ks < 2; ++ks)
        acc[nt] = mfma16(vf[nt][ks], bp[ks], acc[nt]);

    // all my LDS reads from buf[cur] retired -> safe for others to restage it.
    asm volatile("s_waitcnt lgkmcnt(0)\n\ts_barrier" ::: "memory");
  }

  // ---- epilogue: normalize, O^T -> QP (wave-private rows), transpose out
  float t = l0a + l0b;
  t += __shfl_xor(t, 16);
  t += __shfl_xor(t, 32);
  const float inv = 1.0f / t;

  {
    const int pr = (w*16 + l16)*64;
    #pragma unroll
    for (int nt = 0; nt < 4; ++nt){
      int c8  = nt*2 + (quad >> 1);
      int off = ((c8 ^ sw) << 3) + (quad & 1)*4;
      uint2 p;
      p.x = pack_bf2(acc[nt][0]*inv, acc[nt][1]*inv);
      p.y = pack_bf2(acc[nt][2]*inv, acc[nt][3]*inv);
      *(uint2*)&QP[pr + off] = p;
    }
  }
  asm volatile("s_waitcnt lgkmcnt(0)" ::: "memory");
  {
    int r  = w*16 + (lane >> 2);             // wave-private rows: no barrier needed
    int j0 = lane & 3;
    unsigned short* dst = ctx + (size_t)(b*SS + q0 + r)*D_MODEL + h*DK;
    #pragma unroll
    for (int i = 0; i < 2; ++i){
      int j = j0 + i*4;
      uint4 d = *(const uint4*)&QP[r*64 + ((j ^ (r & 7)) << 3)];
      *(uint4*)(dst + j*8) = d;
    }
  }
}

// ---------------------------------------------------------------- launch
extern "C" void kernel_launch(void* const* d_in, const int* in_sizes, int n_in,
                              void* d_out, int out_size, void* d_ws, size_t ws_size,
                              hipStream_t stream) {
  const float* q  = (const float*)d_in[0];
  const float* k  = (const float*)d_in[1];
  const float* v  = (const float*)d_in[2];
  const float* Wq = (const float*)d_in[3];
  const float* bq = (const float*)d_in[4];
  const float* Wk = (const float*)d_in[5];
  const float* bk = (const float*)d_in[6];
  const float* Wv = (const float*)d_in[7];
  const float* bv = (const float*)d_in[8];
  const float* Wo = (const float*)d_in[9];
  const float* bo = (const float*)d_in[10];

  char* ws = (char*)d_ws;
  const size_t TOKB = (size_t)NTOK * D_MODEL * 2;     // 8 MB
  const size_t WB   = (size_t)D_MODEL * D_MODEL * 2;  // 2 MB
  unsigned short* qb  = (unsigned short*)ws;             ws += TOKB;
  unsigned short* kb  = (unsigned short*)ws;             ws += TOKB;
  unsigned short* vb  = (unsigned short*)ws;             ws += TOKB;
  unsigned short* wqb = (unsigned short*)ws;             ws += WB;
  unsigned short* wkb = (unsigned short*)ws;             ws += WB;
  unsigned short* wvb = (unsigned short*)ws;             ws += WB;
  unsigned short* wob = (unsigned short*)ws;             ws += WB;
  unsigned short* Qh  = (unsigned short*)ws;             ws += TOKB;  // [4096][1024], pre-scaled
  unsigned short* Kh  = (unsigned short*)ws;             ws += TOKB;  // [4096][1024]
  unsigned short* Vt  = (unsigned short*)ws;             ws += TOKB;  // [1024][4096], pi-permuted cols
  unsigned short* ctx = (unsigned short*)ws;             ws += TOKB;  // [4096][1024]
  ws += 4096;   // pad: gemm_out's t=15 garbage prefetch reads <=128B past ctx

  cast_bf16_all<<<dim3(2048, 7), 256, 0, stream>>>(q, k, v, Wq, Wk, Wv, Wo,
                                                   qb, kb, vb, wqb, wkb, wvb, wob);
  qkv_gemm<<<dim3(768), 256, 0, stream>>>(qb, kb, vb, wqb, wkb, wvb,
                                          bq, bk, bv, Qh, Kh, Vt);
  attn<<<dim3(SS/128, BB*NHEAD), 512, 0, stream>>>(Qh, Kh, Vt, ctx);
  gemm_out<<<dim3(512), 256, 0, stream>>>(ctx, wob, bo, (float*)d_out);
}